// Round 6
// baseline (335.279 us; speedup 1.0000x reference)
//
#include <hip/hip_runtime.h>
#include <hip/hip_bf16.h>
#include <stdint.h>

// ---------------------------------------------------------------------------
// XFMultiHeadAttention: B=4, S=2048, D=1024, H=16, depth=64.
// I/O f32, compute bf16 MFMA. Pipeline:
//   scan(mask->gather idx) ; transpose4(W) ; cast2(q,k -> bf16) ;
//   fused QKV GEMM (flash-style dbuf: stage(s+1) BEFORE compute(s), ONE
//     __syncthreads/step; A via async16 for z<=1, T14 reg-split for z=2)
//     -> Qh / Kc(swz) / Vc(sigma+swz) ;
//   zero_tails ; flash(compacted keys, fixed-max softmax) ;
//   out GEMM (same dbuf structure) -> d_out
// Memory plan:
//   big ws (>=56.1MB): qb,kb in ws; Kc,Vc in d_out; ONE qkv dispatch (z=3).
//   small ws: qb,kb in d_out; sequential z launches; Kc overwrites qb after
//     z=0, Vc overwrites kb after z=1 (launch order guarantees deadness).
// Kc layout: row s, col = ((dp>>3 ^ (s&7))<<3)|(dp&7)           [bank swizzle]
// Vc layout: row d, within-64-tile col = swz(sigma(off), d):
//   sigma(off) = ((off&15)<<2)|(off>>4) ; then unit-XOR by (d&7)
// flash stages LINEARLY via global_load_lds and applies the same XOR on read.
// Compaction is EXACT (masked rows never computed).
// ---------------------------------------------------------------------------

#define S_LEN 2048
#define NHEAD 16
#define DEPTH 64
#define DMODEL 1024

typedef __bf16 bf16x8 __attribute__((ext_vector_type(8)));
typedef float f32x4 __attribute__((ext_vector_type(4)));
typedef uint16_t u16x8 __attribute__((ext_vector_type(8)));
typedef uint16_t u16x4 __attribute__((ext_vector_type(4)));

#if __has_builtin(__builtin_amdgcn_exp2f)
#define EXP2F(x) __builtin_amdgcn_exp2f(x)   // bare v_exp_f32 (flush-to-zero ok)
#else
#define EXP2F(x) __builtin_exp2f(x)
#endif

__device__ __forceinline__ uint16_t f2bf(float x) {
    __hip_bfloat16 h = __float2bfloat16(x);  // RNE
    union { __hip_bfloat16 h; uint16_t u; } v; v.h = h; return v.u;
}
__device__ __forceinline__ u16x8 pack8(f32x4 a, f32x4 b) {
    u16x8 r;
#pragma unroll
    for (int i = 0; i < 4; ++i) { r[i] = f2bf(a[i]); r[i + 4] = f2bf(b[i]); }
    return r;
}
__device__ __forceinline__ u16x8 cvt8(const float* p) {
    f32x4 lo = *(const f32x4*)p, hi = *(const f32x4*)(p + 4);
    return pack8(lo, hi);
}
// async 16B global->LDS (dest = wave-uniform base + lane*16)  [m97 pattern]
__device__ __forceinline__ void async16(const void* g, void* l) {
    __builtin_amdgcn_global_load_lds((__attribute__((address_space(1))) void*)(g),
                                     (__attribute__((address_space(3))) void*)(l),
                                     16, 0, 0);
}

// ---------------------------------------------------------------------------
// Mask scan: per batch, gidx[b][s'] = original row of s'-th unmasked key; nb[b].
// ---------------------------------------------------------------------------
__global__ void mask_scan(const float* __restrict__ mask, int* __restrict__ gidx,
                          int* __restrict__ nb) {
    __shared__ int part[256];
    const int b = blockIdx.x, tid = threadIdx.x;
    int flags[8], cnt = 0;
#pragma unroll
    for (int i = 0; i < 8; ++i) {
        flags[i] = (mask[b * S_LEN + tid * 8 + i] == 0.0f) ? 1 : 0;
        cnt += flags[i];
    }
    part[tid] = cnt;
    __syncthreads();
    for (int st = 1; st < 256; st <<= 1) {
        int v = (tid >= st) ? part[tid - st] : 0;
        __syncthreads();
        part[tid] += v;
        __syncthreads();
    }
    int run = part[tid] - cnt;  // exclusive offset
#pragma unroll
    for (int i = 0; i < 8; ++i) {
        if (flags[i]) { gidx[b * S_LEN + run] = tid * 8 + i; ++run; }
    }
    if (tid == 255) nb[b] = part[255];
}

// ---------------------------------------------------------------------------
// Weight transpose + bf16 cast: WT4[z][n][k] = bf16(W_z[k][n]); z=Wq,Wk,Wv,Wo
// ---------------------------------------------------------------------------
__global__ void transpose4(const float* __restrict__ w0, const float* __restrict__ w1,
                           const float* __restrict__ w2, const float* __restrict__ w3,
                           uint16_t* __restrict__ dst) {
    __shared__ uint16_t tile[32][33];
    const float* src = (blockIdx.z == 0) ? w0 : (blockIdx.z == 1) ? w1
                     : (blockIdx.z == 2) ? w2 : w3;
    uint16_t* d = dst + (size_t)blockIdx.z * DMODEL * DMODEL;
    int bx = blockIdx.x * 32, by = blockIdx.y * 32;
    int x = threadIdx.x, y0 = threadIdx.y;
#pragma unroll
    for (int i = 0; i < 4; ++i) {
        int y = y0 + i * 8;
        tile[y][x] = f2bf(src[(size_t)(by + y) * DMODEL + bx + x]);
    }
    __syncthreads();
#pragma unroll
    for (int i = 0; i < 4; ++i) {
        int y = y0 + i * 8;
        d[(size_t)(bx + y) * DMODEL + by + x] = tile[x][y];
    }
}

// ---------------------------------------------------------------------------
// cast2: q,k (f32) -> bf16, vectorized 8/thread. grid (4096, 2) x 256.
// ---------------------------------------------------------------------------
__global__ void cast2(const float* __restrict__ a, const float* __restrict__ b,
                      uint16_t* __restrict__ da, uint16_t* __restrict__ db) {
    const float* src = blockIdx.y ? b : a;
    uint16_t* dst = blockIdx.y ? db : da;
    size_t i = ((size_t)blockIdx.x * 256 + threadIdx.x) * 8;
    *(u16x8*)(dst + i) = cvt8(src + i);
}

// ---------------------------------------------------------------------------
// Zero the padding tail of Kc rows / Vc cols in [nb, ceil64(nb)).
// ---------------------------------------------------------------------------
__global__ void zero_tails(const int* __restrict__ nb, uint16_t* __restrict__ Kc,
                           uint16_t* __restrict__ Vc) {
    const int bh = blockIdx.x, b = bh >> 4, t = threadIdx.x;
    const int nbv = nb[b];
    const int end = ((nbv + 63) >> 6) << 6;
    const int tail = end - nbv;  // 0..63
    for (int i = t; i < tail * 64; i += 256) {
        int r = nbv + (i >> 6), c = i & 63;
        Kc[((size_t)bh * S_LEN + r) * DEPTH + c] = 0;
    }
    for (int i = t; i < tail * 64; i += 256) {
        int s = nbv + (i >> 6), d = i & 63;
        int off = s & 63;
        int c1 = ((off & 15) << 2) | (off >> 4);
        int c2 = ((((c1 >> 3) ^ (d & 7)) & 7) << 3) | (c1 & 7);
        Vc[((size_t)bh * DEPTH + d) * S_LEN + (s & ~63) + c2] = 0;
    }
}

// ---------------------------------------------------------------------------
// Fused QKV NT GEMM: out_z = X_z @ W_z^T + bias_z.  128x128 tile, BK=32,
// 4 waves, flash-style dbuf (stage s+1 before compute s, ONE barrier/step).
// z=0: A = qb bf16 async16.  z=1: A = kb bf16 gathered async16.
// z=2: A = v f32 gathered, T14 split (load regs pre-compute, cvt+write post),
//      conflict-free linear LDS writes (byte t*16 / +4KB).
// ---------------------------------------------------------------------------
__global__ __launch_bounds__(256, 3)
void qkv_gemm(const uint16_t* __restrict__ qb, const uint16_t* __restrict__ kb,
              const float* __restrict__ vf, const uint16_t* __restrict__ WT4,
              const float* __restrict__ bq, const float* __restrict__ bk,
              const float* __restrict__ bv, uint16_t* __restrict__ Qh,
              uint16_t* __restrict__ Kc, uint16_t* __restrict__ Vc,
              const int* __restrict__ gidx, const int* __restrict__ nb, int zbase) {
    const int z = zbase + blockIdx.z;
    // XCD swizzle: 8 n-tiles of one A-row-panel land on one XCD (bijective)
    const int fid = blockIdx.x + 8 * blockIdx.y;                  // 0..511
    const int n0 = ((fid >> 3) & 7) * 128;
    const int m0 = ((((fid >> 6) << 3)) | (fid & 7)) * 128;
    const int b_ = m0 >> 11;
    int nbv = 0x7FFFFFFF;
    if (z >= 1) {
        nbv = nb[b_];
        if ((m0 & 2047) >= nbv) return;  // block-uniform early exit
    }

    __shared__ __align__(16) uint16_t As[2][128 * 32];
    __shared__ __align__(16) uint16_t Bs[2][128 * 32];

    const int t = threadIdx.x;
    const int lane = t & 63, quad = lane >> 4, l16 = lane & 15;
    const int w = t >> 6, wm = w >> 1, wn = w & 1;
    const int K = DMODEL;

    const int r_ld = lane >> 2;        // row within 16-row chunk (async path)
    const int c_ld = (lane & 3) * 8;   // 8-col group
    const uint16_t* gB = WT4 + (size_t)z * DMODEL * DMODEL + (size_t)(n0 + r_ld) * K + c_ld;
    const float* bias = (z == 0) ? bq : (z == 1) ? bk : bv;

    // A pointers
    const uint16_t* pA0 = nullptr;  // z<=1 async path (per-chunk)
    const uint16_t* pA1 = nullptr;
    const float* pAa = nullptr;     // z=2 reg path: rows t>>2 and 64+(t>>2)
    const float* pAb = nullptr;
    if (z == 0) {
        pA0 = qb + (size_t)(m0 + (w * 2 + 0) * 16 + r_ld) * K + c_ld;
        pA1 = pA0 + (size_t)16 * K;
    } else if (z == 1) {
        int sp0 = (m0 & 2047) + (w * 2 + 0) * 16 + r_ld;
        int sp1 = sp0 + 16;
        int r0 = (sp0 < nbv) ? gidx[(b_ << 11) + sp0] : 0;
        int r1 = (sp1 < nbv) ? gidx[(b_ << 11) + sp1] : 0;
        pA0 = kb + ((size_t)(b_ << 11) + r0) * K + c_ld;
        pA1 = kb + ((size_t)(b_ << 11) + r1) * K + c_ld;
    } else {
        int spa = (m0 & 2047) + (t >> 2);
        int spb = spa + 64;
        int ra = (spa < nbv) ? gidx[(b_ << 11) + spa] : 0;  // clamp: dummy row 0
        int rb = (spb < nbv) ? gidx[(b_ << 11) + spb] : 0;
        pAa = vf + ((size_t)(b_ << 11) + ra) * K + (t & 3) * 8;
        pAb = vf + ((size_t)(b_ << 11) + rb) * K + (t & 3) * 8;
    }

    f32x4 acc[4][4];
    const f32x4 z4 = {0.f, 0.f, 0.f, 0.f};
#pragma unroll
    for (int mt = 0; mt < 4; ++mt)
#pragma unroll
        for (int nt = 0; nt < 4; ++nt) acc[mt][nt] = z4;

    f32x4 frA[4], frB[4];  // z=2 double prefetch sets (literal indices only)

#define STAGEB(KC, BUF) do {                                                   \
        async16(gB + (size_t)((w * 2 + 0) * 16) * K + (KC), &Bs[(BUF)][(w * 2 + 0) * 512]); \
        async16(gB + (size_t)((w * 2 + 1) * 16) * K + (KC), &Bs[(BUF)][(w * 2 + 1) * 512]); \
    } while (0)
#define STAGEA(KC, BUF) do {                                                   \
        async16(pA0 + (KC), &As[(BUF)][(w * 2 + 0) * 512]);                    \
        async16(pA1 + (KC), &As[(BUF)][(w * 2 + 1) * 512]);                    \
    } while (0)
#define LOADA2(KC, FR) do {                                                    \
        FR[0] = *(const f32x4*)(pAa + (KC));                                   \
        FR[1] = *(const f32x4*)(pAa + (KC) + 4);                               \
        FR[2] = *(const f32x4*)(pAb + (KC));                                   \
        FR[3] = *(const f32x4*)(pAb + (KC) + 4);                               \
    } while (0)
#define WRITEA2(BUF, FR) do {                                                  \
        uint16_t* d_ = &As[(BUF)][0] + t * 8;                                  \
        *(u16x8*)d_ = pack8(FR[0], FR[1]);                                     \
        *(u16x8*)(d_ + 2048) = pack8(FR[2], FR[3]);                            \
    } while (0)
#define COMPUTE(BUF) do {                                                      \
        bf16x8 af[4], bfr[4];                                                  \
        _Pragma("unroll")                                                      \
        for (int mt = 0; mt < 4; ++mt)                                         \
            af[mt] = *(const bf16x8*)&As[(BUF)][(wm * 64 + mt * 16 + l16) * 32 + quad * 8]; \
        _Pragma("unroll")                                                      \
        for (int nt = 0; nt < 4; ++nt)                                         \
            bfr[nt] = *(const bf16x8*)&Bs[(BUF)][(wn * 64 + nt * 16 + l16) * 32 + quad * 8]; \
        __builtin_amdgcn_s_setprio(1);                                         \
        _Pragma("unroll")                                                      \
        for (int mt = 0; mt < 4; ++mt)                                         \
            _Pragma("unroll")                                                  \
            for (int nt = 0; nt < 4; ++nt)                                     \
                acc[mt][nt] = __builtin_amdgcn_mfma_f32_16x16x32_bf16(af[mt], bfr[nt], \
                                                                      acc[mt][nt], 0, 0, 0); \
        __builtin_amdgcn_s_setprio(0);                                         \
    } while (0)

    // prologue: tile 0 into buf 0; z=2 also prefetches A(1) into frA
    STAGEB(0, 0);
    if (z <= 1) { STAGEA(0, 0); }
    else { LOADA2(0, frA); WRITEA2(0, frA); LOADA2(32, frA); }
    __syncthreads();

    for (int s = 0; s < 32; s += 2) {
        // step s (cur=0): stage s+1 -> buf1 before compute
        if (s + 1 < 32) { STAGEB((s + 1) * 32, 1); if (z <= 1) STAGEA((s + 1) * 32, 1); }
        if (z == 2 && s + 2 < 32) LOADA2((s + 2) * 32, frB);  // pre-compute issue
        COMPUTE(0);
        if (z == 2 && s + 1 < 32) WRITEA2(1, frA);            // post-compute write
        __syncthreads();
        // step s+1 (cur=1): stage s+2 -> buf0
        if (s + 2 < 32) { STAGEB((s + 2) * 32, 0); if (z <= 1) STAGEA((s + 2) * 32, 0); }
        if (z == 2 && s + 3 < 32) LOADA2((s + 3) * 32, frA);
        COMPUTE(1);
        if (z == 2 && s + 2 < 32) WRITEA2(0, frB);
        __syncthreads();
    }
#undef STAGEB
#undef STAGEA
#undef LOADA2
#undef WRITEA2
#undef COMPUTE

    // epilogue: C/D layout col=lane&15, row=quad*4+reg
#pragma unroll
    for (int nt = 0; nt < 4; ++nt) {
        int col = n0 + wn * 64 + nt * 16 + l16;
        float bval = bias[col];
        int h = col >> 6, dp = col & 63;
#pragma unroll
        for (int mt = 0; mt < 4; ++mt) {
#pragma unroll
            for (int r = 0; r < 4; ++r) {
                int row = m0 + wm * 64 + mt * 16 + quad * 4 + r;
                float val = acc[mt][nt][r] + bval;
                int b = row >> 11, s = row & 2047;
                if (z == 0) {
                    Qh[(((size_t)(b * NHEAD + h)) * S_LEN + s) * DEPTH + dp] = f2bf(val);
                } else if (z == 1) {
                    if (s < nbv) {
                        int c2 = ((((dp >> 3) ^ (s & 7)) & 7) << 3) | (dp & 7);
                        Kc[(((size_t)(b * NHEAD + h)) * S_LEN + s) * DEPTH + c2] = f2bf(val);
                    }
                } else {
                    if (s < nbv) {
                        int off = s & 63;
                        int c1 = ((off & 15) << 2) | (off >> 4);                  // sigma
                        int c2 = ((((c1 >> 3) ^ (dp & 7)) & 7) << 3) | (c1 & 7);  // bank swz
                        Vc[(((size_t)(b * NHEAD + h)) * DEPTH + dp) * S_LEN
                           + (s & ~63) + c2] = f2bf(val);
                    }
                }
            }
        }
    }
}

// ---------------------------------------------------------------------------
// Out GEMM: d_out = ctx @ Wo^T + bo.  A bf16 head-split + B via async16,
// flash-style dbuf (stage s+1 before compute s, one barrier/step).
// ---------------------------------------------------------------------------
__global__ __launch_bounds__(256, 3)
void out_gemm(const uint16_t* __restrict__ ctx, const uint16_t* __restrict__ Wt,
              const float* __restrict__ bias, float* __restrict__ outp) {
    const int fid = blockIdx.x + 8 * blockIdx.y;
    const int n0 = ((fid >> 3) & 7) * 128;
    const int m0 = ((((fid >> 6) << 3)) | (fid & 7)) * 128;

    __shared__ __align__(16) uint16_t As[2][128 * 32];
    __shared__ __align__(16) uint16_t Bs[2][128 * 32];

    const int t = threadIdx.x;
    const int lane = t & 63, quad = lane >> 4, l16 = lane & 15;
    const int w = t >> 6, wm = w >> 1, wn = w & 1;
    const int K = DMODEL;

    const int r_ld = lane >> 2;
    const int c_ld = (lane & 3) * 8;
    const uint16_t* gB = Wt + (size_t)(n0 + r_ld) * K + c_ld;

    int row0 = m0 + (w * 2 + 0) * 16 + r_ld;
    int row1 = row0 + 16;
    const uint16_t* pA0 = ctx + ((size_t)((row0 >> 11) * NHEAD) * S_LEN + (row0 & 2047)) * DEPTH + c_ld;
    const uint16_t* pA1 = ctx + ((size_t)((row1 >> 11) * NHEAD) * S_LEN + (row1 & 2047)) * DEPTH + c_ld;

    auto stage = [&](int kc, int buf) {
        async16(gB + (size_t)((w * 2 + 0) * 16) * K + kc, &Bs[buf][(w * 2 + 0) * 512]);
        async16(gB + (size_t)((w * 2 + 1) * 16) * K + kc, &Bs[buf][(w * 2 + 1) * 512]);
        size_t aoff = ((size_t)(kc >> 6) << 17) + (kc & 63);  // head stride 2^17
        async16(pA0 + aoff, &As[buf][(w * 2 + 0) * 512]);
        async16(pA1 + aoff, &As[buf][(w * 2 + 1) * 512]);
    };

    f32x4 acc[4][4];
    const f32x4 z4 = {0.f, 0.f, 0.f, 0.f};
#pragma unroll
    for (int mt = 0; mt < 4; ++mt)
#pragma unroll
        for (int nt = 0; nt < 4; ++nt) acc[mt][nt] = z4;

    stage(0, 0);
    __syncthreads();

    for (int s = 0; s < 32; ++s) {
        const int cb = s & 1;
        if (s + 1 < 32) stage((s + 1) * 32, cb ^ 1);
        {
            bf16x8 af[4], bfr[4];
#pragma unroll
            for (int mt = 0; mt < 4; ++mt)
                af[mt] = *(const bf16x8*)&As[cb][(wm * 64 + mt * 16 + l16) * 32 + quad * 8];
#pragma unroll
            for (int nt = 0; nt < 4; ++nt)
                bfr[nt] = *(const bf16x8*)&Bs[cb][(wn * 64 + nt * 16 + l16) * 32 + quad * 8];
            __builtin_amdgcn_s_setprio(1);
#pragma unroll
            for (int mt = 0; mt < 4; ++mt)
#pragma unroll
                for (int nt = 0; nt < 4; ++nt)
                    acc[mt][nt] = __builtin_amdgcn_mfma_f32_16x16x32_bf16(af[mt], bfr[nt],
                                                                          acc[mt][nt], 0, 0, 0);
            __builtin_amdgcn_s_setprio(0);
        }
        __syncthreads();
    }

#pragma unroll
    for (int nt = 0; nt < 4; ++nt) {
        int col = n0 + wn * 64 + nt * 16 + l16;
        float bval = bias[col];
#pragma unroll
        for (int mt = 0; mt < 4; ++mt) {
#pragma unroll
            for (int r = 0; r < 4; ++r) {
                int row = m0 + wm * 64 + mt * 16 + quad * 4 + r;
                outp[(size_t)row * DMODEL + col] = acc[mt][nt][r] + bval;
            }
        }
    }
}

// ---------------------------------------------------------------------------
// Flash attention over COMPACTED keys, fixed-max softmax (m=12, exp2-domain).
// Grid (16 q-tiles, 64 bh), XCD-swizzled. 256 thr (4 waves), 32 q-rows/wave.
// LDS 41KB -> 3 blocks/CU. One __syncthreads per tile; prefetch in flight.
// ---------------------------------------------------------------------------
__global__ __launch_bounds__(256, 3)
void flash_attn(const uint16_t* __restrict__ Qh, const uint16_t* __restrict__ Kc,
                const uint16_t* __restrict__ Vc, const int* __restrict__ nb,
                uint16_t* __restrict__ ctx) {
    __shared__ __align__(16) uint16_t Ks[2][64 * 64];
    __shared__ __align__(16) uint16_t Vs[2][64 * 64];
    __shared__ __align__(16) uint16_t Ps[4][16 * 72];

    const int t = threadIdx.x;
    const int w = t >> 6, lane = t & 63, quad = lane >> 4, l16 = lane & 15;
    // XCD swizzle: 16 q-tiles sharing one bh's K/V land on one XCD (bijective)
    const int fid = blockIdx.x + 16 * blockIdx.y;                // 0..1023
    const int q0 = ((fid >> 3) & 15) * 128;
    const int bh = ((fid >> 7) << 3) | (fid & 7);
    const int b = bh >> 4;
    const int nbv = nb[b];
    const int ntiles = (nbv + 63) >> 6;

    const int srow8 = lane >> 3, scol8 = (lane & 7) * 8;
    const uint16_t* pKn = Kc + ((size_t)bh * S_LEN + w * 16 + srow8) * DEPTH + scol8;
    const uint16_t* pVn = Vc + ((size_t)bh * DEPTH + w * 16 + srow8) * S_LEN + scol8;
    uint16_t* dK0 = &Ks[0][w * 16 * 64];
    uint16_t* dK1 = &Ks[1][w * 16 * 64];
    uint16_t* dV0 = &Vs[0][w * 16 * 64];
    uint16_t* dV1 = &Vs[1][w * 16 * 64];

    bf16x8 aq[2][2];
#pragma unroll
    for (int mt = 0; mt < 2; ++mt)
#pragma unroll
        for (int kc = 0; kc < 2; ++kc)
            aq[mt][kc] = *(const bf16x8*)(Qh + ((size_t)bh * S_LEN + q0 + w * 32 + mt * 16 + l16) * DEPTH
                                          + kc * 32 + quad * 8);

    float lrow[2][4];
    f32x4 Oacc[2][4];
    const f32x4 z4 = {0.f, 0.f, 0.f, 0.f};
#pragma unroll
    for (int mt = 0; mt < 2; ++mt)
#pragma unroll
        for (int r = 0; r < 4; ++r) lrow[mt][r] = 0.f;
#pragma unroll
    for (int mt = 0; mt < 2; ++mt)
#pragma unroll
        for (int nt = 0; nt < 4; ++nt) Oacc[mt][nt] = z4;

    const float C2 = 0.18033688f;
    const float M2 = 17.312340f;
    const int swzk = l16 & 7;

    async16(pKn, dK0); async16(pKn + 8 * DEPTH, dK0 + 8 * 64);
    async16(pVn, dV0); async16(pVn + 8 * S_LEN, dV0 + 8 * 64);
    pKn += 64 * DEPTH; pVn += 64;
    __syncthreads();

    for (int kt = 0; kt < ntiles; ++kt) {
        const int cur = kt & 1;
        if (kt + 1 < ntiles) {
            uint16_t* dK = cur ? dK0 : dK1;
            uint16_t* dV = cur ? dV0 : dV1;
            async16(pKn, dK); async16(pKn + 8 * DEPTH, dK + 8 * 64);
            async16(pVn, dV); async16(pVn + 8 * S_LEN, dV + 8 * 64);
            pKn += 64 * DEPTH; pVn += 64;
        }
        const uint16_t* ksrc = cur ? &Ks[1][0] : &Ks[0][0];
        const uint16_t* vsrc = cur ? &Vs[1][0] : &Vs[0][0];
        const int k0 = kt * 64;

        float pen[4];
#pragma unroll
        for (int nt = 0; nt < 4; ++nt)
            pen[nt] = (k0 + nt * 16 + l16 < nbv) ? -M2 : -2e9f;

        f32x4 sacc[2][4];
#pragma unroll
        for (int mt = 0; mt < 2; ++mt)
#pragma unroll
            for (int nt = 0; nt < 4; ++nt) sacc[mt][nt] = z4;
        __builtin_amdgcn_s_setprio(1);
#pragma unroll
        for (int kc = 0; kc < 2; ++kc) {
#pragma unroll
            for (int nt = 0; nt < 4; ++nt) {
                bf16x8 bk = *(const bf16x8*)&ksrc[(nt * 16 + l16) * 64 + (((kc * 4 + quad) ^ swzk) << 3)];
#pragma unroll
                for (int mt = 0; mt < 2; ++mt)
                    sacc[mt][nt] = __builtin_amdgcn_mfma_f32_16x16x32_bf16(aq[mt][kc], bk,
                                                                           sacc[mt][nt], 0, 0, 0);
            }
        }
        __builtin_amdgcn_s_setprio(0);

        bf16x8 bvr[2][4];
#pragma unroll
        for (int kc = 0; kc < 2; ++kc)
#pragma unroll
            for (int nt = 0; nt < 4; ++nt)
                bvr[kc][nt] = *(const bf16x8*)&vsrc[(nt * 16 + l16) * 64 + (((kc * 4 + quad) ^ swzk) << 3)];

#pragma unroll
        for (int mt = 0; mt < 2; ++mt) {
#pragma unroll
            for (int r = 0; r < 4; ++r) {
                float p0 = EXP2F(fmaf(sacc[mt][0][r], C2, pen[0]));
                float p1 = EXP2F(fmaf(sacc[mt][1][r], C2, pen[1]));
                float p2 = EXP2F(fmaf(sacc[mt][2][r], C2, pen[2]));
                float p3 = EXP2F(fmaf(sacc[mt][3][r], C2, pen[3]));
                lrow[mt][r] += (p0 + p1) + (p2 + p3);
                u16x4 pk;
                pk[0] = f2bf(p0); pk[1] = f2bf(p1); pk[2] = f2bf(p2); pk[3] = f2bf(p3);
                *(u16x4*)&Ps[w][(quad * 4 + r) * 72 + l16 * 4] = pk;
            }
            __builtin_amdgcn_s_setprio(1);
#pragma unroll
            for (int kc = 0; kc < 2; ++kc) {
                bf16x8 ap = *(const bf16x8*)&Ps[w][l16 * 72 + kc * 32 + quad * 8];
#pragma unroll
                for (int nt = 0; nt < 4; ++nt)
                    Oacc[mt][nt] = __builtin_amdgcn_mfma_f32_16x16x32_bf16(ap, bvr[kc][nt],
                                                                           Oacc[mt][nt], 0, 0, 0);
            }
            __builtin_amdgcn_s_setprio(0);
        }
        __syncthreads();
    }

#pragma unroll
    for (int mt = 0; mt < 2; ++mt) {
#pragma unroll
        for (int r = 0; r < 4; ++r) {
            float rs = lrow[mt][r];
            rs += __shfl_xor(rs, 1);
            rs += __shfl_xor(rs, 2);
            rs += __shfl_xor(rs, 4);
            rs += __shfl_xor(rs, 8);
            float inv = 1.0f / rs;
            int srow = q0 + w * 32 + mt * 16 + quad * 4 + r;
            size_t base = ((size_t)bh * S_LEN + srow) * DEPTH;
#pragma unroll
            for (int nt = 0; nt < 4; ++nt)
                ctx[base + nt * 16 + l16] = f2bf(Oacc[mt][nt][r] * inv);
        }
    }
}

// ---------------------------------------------------------------------------
extern "C" void kernel_launch(void* const* d_in, const int* in_sizes, int n_in,
                              void* d_out, int out_size, void* d_ws, size_t ws_size,
                              hipStream_t stream) {
    const float* v    = (const float*)d_in[0];
    const float* k    = (const float*)d_in[1];
    const float* q    = (const float*)d_in[2];
    const float* mask = (const float*)d_in[3];
    const float* Wq   = (const float*)d_in[4];
    const float* bq   = (const float*)d_in[5];
    const float* Wk   = (const float*)d_in[6];
    const float* bk   = (const float*)d_in[7];
    const float* Wv   = (const float*)d_in[8];
    const float* bv   = (const float*)d_in[9];
    const float* Wo   = (const float*)d_in[10];
    const float* bo   = (const float*)d_in[11];

    // ws: WT4(8MB) + Qh(16MB) + gidx(32KB) + nb(16B) [+ qb,kb(32MB) if big ws]
    char* p = (char*)d_ws;
    uint16_t* WT4 = (uint16_t*)p; p += (size_t)4 * DMODEL * DMODEL * 2;
    uint16_t* Qh  = (uint16_t*)p; p += (size_t)64 * S_LEN * DEPTH * 2;
    int* gidx     = (int*)p;      p += (size_t)4 * S_LEN * 4;
    int* nb       = (int*)p;      p += 16;
    size_t used = (size_t)(p - (char*)d_ws);
    const size_t half16 = (size_t)8192 * DMODEL * 2;  // 16MB (bf16 8192x1024)

    const bool bigws = (ws_size >= used + 2 * half16);
    uint16_t *qb, *kb, *Kc, *Vc;
    if (bigws) {
        qb = (uint16_t*)((char*)d_ws + used);
        kb = qb + (size_t)8192 * DMODEL;
        Kc = (uint16_t*)d_out;                       // d_out: [Kc 16MB][Vc 16MB]
        Vc = Kc + (size_t)64 * S_LEN * DEPTH;
    } else {
        qb = (uint16_t*)d_out;                       // d_out: [qb->Kc][kb->Vc]
        kb = qb + (size_t)8192 * DMODEL;
        Kc = qb;                                     // overwrites qb after z=0
        Vc = kb;                                     // overwrites kb after z=1
    }

    mask_scan<<<4, 256, 0, stream>>>(mask, gidx, nb);
    transpose4<<<dim3(32, 32, 4), dim3(32, 8), 0, stream>>>(Wq, Wk, Wv, Wo, WT4);
    cast2<<<dim3(4096, 2), 256, 0, stream>>>(q, k, qb, kb);

    if (bigws) {
        qkv_gemm<<<dim3(8, 64, 3), 256, 0, stream>>>(qb, kb, v, WT4, bq, bk, bv,
                                                     Qh, Kc, Vc, gidx, nb, 0);
    } else {
        // sequential: z0 reads qb -> Qh; z1 reads kb -> Kc(=qb region, dead);
        // z2 reads v f32 -> Vc(=kb region, dead after z1).
        qkv_gemm<<<dim3(8, 64, 1), 256, 0, stream>>>(qb, kb, v, WT4, bq, bk, bv,
                                                     Qh, Kc, Vc, gidx, nb, 0);
        qkv_gemm<<<dim3(8, 64, 1), 256, 0, stream>>>(qb, kb, v, WT4, bq, bk, bv,
                                                     Qh, Kc, Vc, gidx, nb, 1);
        qkv_gemm<<<dim3(8, 64, 1), 256, 0, stream>>>(qb, kb, v, WT4, bq, bk, bv,
                                                     Qh, Kc, Vc, gidx, nb, 2);
    }
    zero_tails<<<64, 256, 0, stream>>>(nb, Kc, Vc);

    flash_attn<<<dim3(16, 64), 256, 0, stream>>>(Qh, Kc, Vc, nb, Qh /*ctx*/);

    out_gemm<<<dim3(8, 64), 256, 0, stream>>>(Qh, WT4 + (size_t)3 * DMODEL * DMODEL,
                                              bo, (float*)d_out);
}

// Round 8
// 328.081 us; speedup vs baseline: 1.0219x; 1.0219x over previous
//
#include <hip/hip_runtime.h>
#include <hip/hip_bf16.h>
#include <stdint.h>

// ---------------------------------------------------------------------------
// XFMultiHeadAttention: B=4, S=2048, D=1024, H=16, depth=64.
// I/O f32, compute bf16 MFMA. Pipeline:
//   scan(mask->gather idx) ; transpose4(W) ; cast2(q,k -> bf16) ;
//   fused QKV GEMM (round-2 depth-0 loop: stage -> barrier -> compute;
//     z=2 epilogue via LDS-transpose -> COALESCED Vc writes) ;
//   zero_tails ; flash(compacted keys, fixed-max softmax) ;
//   out GEMM (dbuf) -> d_out
// Memory plan:
//   big ws (>=56.1MB): qb,kb in ws; Kc,Vc in d_out; ONE qkv dispatch (z=3).
//   small ws: qb,kb in d_out; sequential z launches; Kc overwrites qb after
//     z=0, Vc overwrites kb after z=1.
// Kc layout: row s, col = ((dp>>3 ^ (s&7))<<3)|(dp&7)           [bank swizzle]
// Vc layout: row d, within-64-tile col = swz(sigma(off), d):
//   sigma(off) = ((off&15)<<2)|(off>>4) ; then unit-XOR by (d&7)
// flash stages LINEARLY via global_load_lds and applies the same XOR on read.
// Compaction is EXACT. z=2 writes full [m0,m0+128) s-ranges (LOCAL s =
// m0&2047 — r7 crash was using global m0 here); garbage in [nbv, ceil64)
// is re-zeroed by zero_tails; beyond ceil64 is never read by flash.
// ---------------------------------------------------------------------------

#define S_LEN 2048
#define NHEAD 16
#define DEPTH 64
#define DMODEL 1024

typedef __bf16 bf16x8 __attribute__((ext_vector_type(8)));
typedef float f32x4 __attribute__((ext_vector_type(4)));
typedef uint16_t u16x8 __attribute__((ext_vector_type(8)));
typedef uint16_t u16x4 __attribute__((ext_vector_type(4)));

#if __has_builtin(__builtin_amdgcn_exp2f)
#define EXP2F(x) __builtin_amdgcn_exp2f(x)   // bare v_exp_f32 (flush-to-zero ok)
#else
#define EXP2F(x) __builtin_exp2f(x)
#endif

__device__ __forceinline__ uint16_t f2bf(float x) {
    __hip_bfloat16 h = __float2bfloat16(x);  // RNE
    union { __hip_bfloat16 h; uint16_t u; } v; v.h = h; return v.u;
}
__device__ __forceinline__ u16x8 pack8(f32x4 a, f32x4 b) {
    u16x8 r;
#pragma unroll
    for (int i = 0; i < 4; ++i) { r[i] = f2bf(a[i]); r[i + 4] = f2bf(b[i]); }
    return r;
}
__device__ __forceinline__ u16x8 cvt8(const float* p) {
    f32x4 lo = *(const f32x4*)p, hi = *(const f32x4*)(p + 4);
    return pack8(lo, hi);
}
// async 16B global->LDS (dest = wave-uniform base + lane*16)  [m97 pattern]
__device__ __forceinline__ void async16(const void* g, void* l) {
    __builtin_amdgcn_global_load_lds((__attribute__((address_space(1))) void*)(g),
                                     (__attribute__((address_space(3))) void*)(l),
                                     16, 0, 0);
}

// ---------------------------------------------------------------------------
// Mask scan: per batch, gidx[b][s'] = original row of s'-th unmasked key; nb[b].
// ---------------------------------------------------------------------------
__global__ void mask_scan(const float* __restrict__ mask, int* __restrict__ gidx,
                          int* __restrict__ nb) {
    __shared__ int part[256];
    const int b = blockIdx.x, tid = threadIdx.x;
    int flags[8], cnt = 0;
#pragma unroll
    for (int i = 0; i < 8; ++i) {
        flags[i] = (mask[b * S_LEN + tid * 8 + i] == 0.0f) ? 1 : 0;
        cnt += flags[i];
    }
    part[tid] = cnt;
    __syncthreads();
    for (int st = 1; st < 256; st <<= 1) {
        int v = (tid >= st) ? part[tid - st] : 0;
        __syncthreads();
        part[tid] += v;
        __syncthreads();
    }
    int run = part[tid] - cnt;  // exclusive offset
#pragma unroll
    for (int i = 0; i < 8; ++i) {
        if (flags[i]) { gidx[b * S_LEN + run] = tid * 8 + i; ++run; }
    }
    if (tid == 255) nb[b] = part[255];
}

// ---------------------------------------------------------------------------
// Weight transpose + bf16 cast: WT4[z][n][k] = bf16(W_z[k][n]); z=Wq,Wk,Wv,Wo
// ---------------------------------------------------------------------------
__global__ void transpose4(const float* __restrict__ w0, const float* __restrict__ w1,
                           const float* __restrict__ w2, const float* __restrict__ w3,
                           uint16_t* __restrict__ dst) {
    __shared__ uint16_t tile[32][33];
    const float* src = (blockIdx.z == 0) ? w0 : (blockIdx.z == 1) ? w1
                     : (blockIdx.z == 2) ? w2 : w3;
    uint16_t* d = dst + (size_t)blockIdx.z * DMODEL * DMODEL;
    int bx = blockIdx.x * 32, by = blockIdx.y * 32;
    int x = threadIdx.x, y0 = threadIdx.y;
#pragma unroll
    for (int i = 0; i < 4; ++i) {
        int y = y0 + i * 8;
        tile[y][x] = f2bf(src[(size_t)(by + y) * DMODEL + bx + x]);
    }
    __syncthreads();
#pragma unroll
    for (int i = 0; i < 4; ++i) {
        int y = y0 + i * 8;
        d[(size_t)(bx + y) * DMODEL + by + x] = tile[x][y];
    }
}

// ---------------------------------------------------------------------------
// cast2: q,k (f32) -> bf16, vectorized 8/thread. grid (4096, 2) x 256.
// ---------------------------------------------------------------------------
__global__ void cast2(const float* __restrict__ a, const float* __restrict__ b,
                      uint16_t* __restrict__ da, uint16_t* __restrict__ db) {
    const float* src = blockIdx.y ? b : a;
    uint16_t* dst = blockIdx.y ? db : da;
    size_t i = ((size_t)blockIdx.x * 256 + threadIdx.x) * 8;
    *(u16x8*)(dst + i) = cvt8(src + i);
}

// ---------------------------------------------------------------------------
// Zero the padding tail of Kc rows / Vc cols in [nb, ceil64(nb)).
// ---------------------------------------------------------------------------
__global__ void zero_tails(const int* __restrict__ nb, uint16_t* __restrict__ Kc,
                           uint16_t* __restrict__ Vc) {
    const int bh = blockIdx.x, b = bh >> 4, t = threadIdx.x;
    const int nbv = nb[b];
    const int end = ((nbv + 63) >> 6) << 6;
    const int tail = end - nbv;  // 0..63
    for (int i = t; i < tail * 64; i += 256) {
        int r = nbv + (i >> 6), c = i & 63;
        Kc[((size_t)bh * S_LEN + r) * DEPTH + c] = 0;
    }
    for (int i = t; i < tail * 64; i += 256) {
        int s = nbv + (i >> 6), d = i & 63;
        int off = s & 63;
        int c1 = ((off & 15) << 2) | (off >> 4);
        int c2 = ((((c1 >> 3) ^ (d & 7)) & 7) << 3) | (c1 & 7);
        Vc[((size_t)bh * DEPTH + d) * S_LEN + (s & ~63) + c2] = 0;
    }
}

// ---------------------------------------------------------------------------
// Fused QKV NT GEMM: out_z = X_z @ W_z^T + bias_z.  128x128 tile, BK=32,
// 4 waves, depth-0 loop (stage -> barrier -> compute -> barrier). z=0:
// A=qb async16. z=1: A=kb gathered async16. z=2: A=v f32 gathered, cvt in
// regs, conflict-free linear LDS write; epilogue via LDS-transpose ->
// coalesced Vc stores.
// ---------------------------------------------------------------------------
__global__ __launch_bounds__(256, 3)
void qkv_gemm(const uint16_t* __restrict__ qb, const uint16_t* __restrict__ kb,
              const float* __restrict__ vf, const uint16_t* __restrict__ WT4,
              const float* __restrict__ bq, const float* __restrict__ bk,
              const float* __restrict__ bv, uint16_t* __restrict__ Qh,
              uint16_t* __restrict__ Kc, uint16_t* __restrict__ Vc,
              const int* __restrict__ gidx, const int* __restrict__ nb, int zbase) {
    const int z = zbase + blockIdx.z;
    // XCD swizzle: 8 n-tiles of one A-row-panel land on one XCD (bijective)
    const int fid = blockIdx.x + 8 * blockIdx.y;                  // 0..511
    const int n0 = ((fid >> 3) & 7) * 128;
    const int m0 = ((((fid >> 6) << 3)) | (fid & 7)) * 128;
    const int b_ = m0 >> 11;
    int nbv = 0x7FFFFFFF;
    if (z >= 1) {
        nbv = nb[b_];
        if ((m0 & 2047) >= nbv) return;  // block-uniform early exit
    }

    // 32 KB shared: K-loop uses first 16 KB as As|Bs; z=2 epilogue reuses all
    __shared__ __align__(16) uint16_t SH[128 * 128];
    uint16_t* As = SH;               // [128 rows][32 cols] bf16, 8 KB
    uint16_t* Bs = SH + 128 * 32;    // 8 KB

    const int t = threadIdx.x;
    const int lane = t & 63, quad = lane >> 4, l16 = lane & 15;
    const int w = t >> 6, wm = w >> 1, wn = w & 1;
    const int K = DMODEL;

    const int r_ld = lane >> 2;        // row within 16-row chunk (async path)
    const int c_ld = (lane & 3) * 8;   // 8-col group
    const uint16_t* gB = WT4 + (size_t)z * DMODEL * DMODEL + (size_t)(n0 + r_ld) * K + c_ld;
    const float* bias = (z == 0) ? bq : (z == 1) ? bk : bv;

    // A pointers
    const uint16_t* pA0 = nullptr;  // z<=1 async path (per-chunk)
    const uint16_t* pA1 = nullptr;
    const float* pAa = nullptr;     // z=2 reg path: rows t>>2 and 64+(t>>2)
    const float* pAb = nullptr;
    if (z == 0) {
        pA0 = qb + (size_t)(m0 + (w * 2 + 0) * 16 + r_ld) * K + c_ld;
        pA1 = pA0 + (size_t)16 * K;
    } else if (z == 1) {
        int sp0 = (m0 & 2047) + (w * 2 + 0) * 16 + r_ld;
        int sp1 = sp0 + 16;
        int r0 = (sp0 < nbv) ? gidx[(b_ << 11) + sp0] : 0;
        int r1 = (sp1 < nbv) ? gidx[(b_ << 11) + sp1] : 0;
        pA0 = kb + ((size_t)(b_ << 11) + r0) * K + c_ld;
        pA1 = kb + ((size_t)(b_ << 11) + r1) * K + c_ld;
    } else {
        int spa = (m0 & 2047) + (t >> 2);
        int spb = spa + 64;
        int ra = (spa < nbv) ? gidx[(b_ << 11) + spa] : 0;  // clamp: dummy row 0
        int rb = (spb < nbv) ? gidx[(b_ << 11) + spb] : 0;
        pAa = vf + ((size_t)(b_ << 11) + ra) * K + (t & 3) * 8;
        pAb = vf + ((size_t)(b_ << 11) + rb) * K + (t & 3) * 8;
    }

    f32x4 acc[4][4];
    const f32x4 z4 = {0.f, 0.f, 0.f, 0.f};
#pragma unroll
    for (int mt = 0; mt < 4; ++mt)
#pragma unroll
        for (int nt = 0; nt < 4; ++nt) acc[mt][nt] = z4;

    for (int kc = 0; kc < K; kc += 32) {
        async16(gB + (size_t)((w * 2 + 0) * 16) * K + kc, &Bs[(w * 2 + 0) * 512]);
        async16(gB + (size_t)((w * 2 + 1) * 16) * K + kc, &Bs[(w * 2 + 1) * 512]);
        if (z <= 1) {
            async16(pA0 + kc, &As[(w * 2 + 0) * 512]);
            async16(pA1 + kc, &As[(w * 2 + 1) * 512]);
        } else {
            // rows t>>2 and 64+(t>>2), cols (t&3)*8..+7; linear byte t*16 write
            f32x4 a0 = *(const f32x4*)(pAa + kc), a1 = *(const f32x4*)(pAa + kc + 4);
            f32x4 b0 = *(const f32x4*)(pAb + kc), b1 = *(const f32x4*)(pAb + kc + 4);
            uint16_t* d_ = As + t * 8;
            *(u16x8*)d_ = pack8(a0, a1);
            *(u16x8*)(d_ + 2048) = pack8(b0, b1);
        }
        __syncthreads();

        bf16x8 af[4], bfr[4];
#pragma unroll
        for (int mt = 0; mt < 4; ++mt)
            af[mt] = *(const bf16x8*)&As[(wm * 64 + mt * 16 + l16) * 32 + quad * 8];
#pragma unroll
        for (int nt = 0; nt < 4; ++nt)
            bfr[nt] = *(const bf16x8*)&Bs[(wn * 64 + nt * 16 + l16) * 32 + quad * 8];
#pragma unroll
        for (int mt = 0; mt < 4; ++mt)
#pragma unroll
            for (int nt = 0; nt < 4; ++nt)
                acc[mt][nt] = __builtin_amdgcn_mfma_f32_16x16x32_bf16(af[mt], bfr[nt],
                                                                      acc[mt][nt], 0, 0, 0);
        __syncthreads();
    }

    if (z == 2) {
        // ---- epilogue: LDS-transpose then COALESCED Vc writes ----
        // Stage bf16(acc+bias) into SH at [col c][layout byte j],
        // XOR-swizzled by ((c&15)<<4) for conflict-free b16 writes/b128 reads.
#pragma unroll
        for (int nt = 0; nt < 4; ++nt) {
            int c = wn * 64 + nt * 16 + l16;            // local col 0..127
            float bval = bias[n0 + c];
            int dp = (n0 + c) & 63;
            int key = (c & 15) << 4;
            char* rowp = (char*)SH + c * 256;
#pragma unroll
            for (int mt = 0; mt < 4; ++mt) {
#pragma unroll
                for (int r = 0; r < 4; ++r) {
                    int rowl = wm * 64 + mt * 16 + quad * 4 + r;
                    int off = rowl & 63, half = rowl >> 6;
                    int c1 = ((off & 15) << 2) | (off >> 4);                  // sigma
                    int c2 = ((((c1 >> 3) ^ (dp & 7)) & 7) << 3) | (c1 & 7);  // bank swz
                    int j = half * 128 + c2 * 2;        // byte pos in 256B run
                    *(uint16_t*)(rowp + (j ^ key)) = f2bf(acc[mt][nt][r] + bval);
                }
            }
        }
        __syncthreads();
        // Write phase: 128 cols x 256B contiguous runs; 16B granules.
        // task = p*256+t: c = task>>4, g = task&15. Lanes share c -> coalesced.
        const int sloc = m0 & 2047;  // LOCAL s base (r7 bug: used global m0)
#pragma unroll
        for (int p = 0; p < 8; ++p) {
            int task = p * 256 + t;
            int c = task >> 4, g = task & 15;
            int colg = n0 + c, h = colg >> 6, dp = colg & 63;
            u16x8 vdat = *(const u16x8*)((const char*)SH + c * 256
                                         + ((g * 16) ^ ((c & 15) << 4)));
            size_t elem = ((size_t)(b_ * NHEAD + h) * DEPTH + dp) * S_LEN + sloc + g * 8;
            *(u16x8*)(Vc + elem) = vdat;
        }
        return;
    }

    // z<=1 epilogue: C/D layout col=lane&15, row=quad*4+reg (direct stores)
#pragma unroll
    for (int nt = 0; nt < 4; ++nt) {
        int col = n0 + wn * 64 + nt * 16 + l16;
        float bval = bias[col];
        int h = col >> 6, dp = col & 63;
#pragma unroll
        for (int mt = 0; mt < 4; ++mt) {
#pragma unroll
            for (int r = 0; r < 4; ++r) {
                int row = m0 + wm * 64 + mt * 16 + quad * 4 + r;
                float val = acc[mt][nt][r] + bval;
                int b = row >> 11, s = row & 2047;
                if (z == 0) {
                    Qh[(((size_t)(b * NHEAD + h)) * S_LEN + s) * DEPTH + dp] = f2bf(val);
                } else {
                    if (s < nbv) {
                        int c2 = ((((dp >> 3) ^ (s & 7)) & 7) << 3) | (dp & 7);
                        Kc[(((size_t)(b * NHEAD + h)) * S_LEN + s) * DEPTH + c2] = f2bf(val);
                    }
                }
            }
        }
    }
}

// ---------------------------------------------------------------------------
// Out GEMM: d_out = ctx @ Wo^T + bo.  A bf16 head-split + B via async16,
// flash-style dbuf (stage s+1 before compute s, one barrier/step).
// ---------------------------------------------------------------------------
__global__ __launch_bounds__(256, 3)
void out_gemm(const uint16_t* __restrict__ ctx, const uint16_t* __restrict__ Wt,
              const float* __restrict__ bias, float* __restrict__ outp) {
    const int fid = blockIdx.x + 8 * blockIdx.y;
    const int n0 = ((fid >> 3) & 7) * 128;
    const int m0 = ((((fid >> 6) << 3)) | (fid & 7)) * 128;

    __shared__ __align__(16) uint16_t As[2][128 * 32];
    __shared__ __align__(16) uint16_t Bs[2][128 * 32];

    const int t = threadIdx.x;
    const int lane = t & 63, quad = lane >> 4, l16 = lane & 15;
    const int w = t >> 6, wm = w >> 1, wn = w & 1;
    const int K = DMODEL;

    const int r_ld = lane >> 2;
    const int c_ld = (lane & 3) * 8;
    const uint16_t* gB = Wt + (size_t)(n0 + r_ld) * K + c_ld;

    int row0 = m0 + (w * 2 + 0) * 16 + r_ld;
    int row1 = row0 + 16;
    const uint16_t* pA0 = ctx + ((size_t)((row0 >> 11) * NHEAD) * S_LEN + (row0 & 2047)) * DEPTH + c_ld;
    const uint16_t* pA1 = ctx + ((size_t)((row1 >> 11) * NHEAD) * S_LEN + (row1 & 2047)) * DEPTH + c_ld;

    auto stage = [&](int kc, int buf) {
        async16(gB + (size_t)((w * 2 + 0) * 16) * K + kc, &Bs[buf][(w * 2 + 0) * 512]);
        async16(gB + (size_t)((w * 2 + 1) * 16) * K + kc, &Bs[buf][(w * 2 + 1) * 512]);
        size_t aoff = ((size_t)(kc >> 6) << 17) + (kc & 63);  // head stride 2^17
        async16(pA0 + aoff, &As[buf][(w * 2 + 0) * 512]);
        async16(pA1 + aoff, &As[buf][(w * 2 + 1) * 512]);
    };

    f32x4 acc[4][4];
    const f32x4 z4 = {0.f, 0.f, 0.f, 0.f};
#pragma unroll
    for (int mt = 0; mt < 4; ++mt)
#pragma unroll
        for (int nt = 0; nt < 4; ++nt) acc[mt][nt] = z4;

    stage(0, 0);
    __syncthreads();

    for (int s = 0; s < 32; ++s) {
        const int cb = s & 1;
        if (s + 1 < 32) stage((s + 1) * 32, cb ^ 1);
        {
            bf16x8 af[4], bfr[4];
#pragma unroll
            for (int mt = 0; mt < 4; ++mt)
                af[mt] = *(const bf16x8*)&As[cb][(wm * 64 + mt * 16 + l16) * 32 + quad * 8];
#pragma unroll
            for (int nt = 0; nt < 4; ++nt)
                bfr[nt] = *(const bf16x8*)&Bs[cb][(wn * 64 + nt * 16 + l16) * 32 + quad * 8];
            __builtin_amdgcn_s_setprio(1);
#pragma unroll
            for (int mt = 0; mt < 4; ++mt)
#pragma unroll
                for (int nt = 0; nt < 4; ++nt)
                    acc[mt][nt] = __builtin_amdgcn_mfma_f32_16x16x32_bf16(af[mt], bfr[nt],
                                                                          acc[mt][nt], 0, 0, 0);
            __builtin_amdgcn_s_setprio(0);
        }
        __syncthreads();
    }

#pragma unroll
    for (int nt = 0; nt < 4; ++nt) {
        int col = n0 + wn * 64 + nt * 16 + l16;
        float bval = bias[col];
#pragma unroll
        for (int mt = 0; mt < 4; ++mt) {
#pragma unroll
            for (int r = 0; r < 4; ++r) {
                int row = m0 + wm * 64 + mt * 16 + quad * 4 + r;
                outp[(size_t)row * DMODEL + col] = acc[mt][nt][r] + bval;
            }
        }
    }
}

// ---------------------------------------------------------------------------
// Flash attention over COMPACTED keys, fixed-max softmax (m=12, exp2-domain).
// Grid (16 q-tiles, 64 bh), XCD-swizzled. 256 thr (4 waves), 32 q-rows/wave.
// LDS 41KB -> 3 blocks/CU. One __syncthreads per tile; prefetch in flight.
// ---------------------------------------------------------------------------
__global__ __launch_bounds__(256, 3)
void flash_attn(const uint16_t* __restrict__ Qh, const uint16_t* __restrict__ Kc,
                const uint16_t* __restrict__ Vc, const int* __restrict__ nb,
                uint16_t* __restrict__ ctx) {
    __shared__ __align__(16) uint16_t Ks[2][64 * 64];
    __shared__ __align__(16) uint16_t Vs[2][64 * 64];
    __shared__ __align__(16) uint16_t Ps[4][16 * 72];

    const int t = threadIdx.x;
    const int w = t >> 6, lane = t & 63, quad = lane >> 4, l16 = lane & 15;
    // XCD swizzle: 16 q-tiles sharing one bh's K/V land on one XCD (bijective)
    const int fid = blockIdx.x + 16 * blockIdx.y;                // 0..1023
    const int q0 = ((fid >> 3) & 15) * 128;
    const int bh = ((fid >> 7) << 3) | (fid & 7);
    const int b = bh >> 4;
    const int nbv = nb[b];
    const int ntiles = (nbv + 63) >> 6;

    const int srow8 = lane >> 3, scol8 = (lane & 7) * 8;
    const uint16_t* pKn = Kc + ((size_t)bh * S_LEN + w * 16 + srow8) * DEPTH + scol8;
    const uint16_t* pVn = Vc + ((size_t)bh * DEPTH + w * 16 + srow8) * S_LEN + scol8;
    uint16_t* dK0 = &Ks[0][w * 16 * 64];
    uint16_t* dK1 = &Ks[1][w * 16 * 64];
    uint16_t* dV0 = &Vs[0][w * 16 * 64];
    uint16_t* dV1 = &Vs[1][w * 16 * 64];

    bf16x8 aq[2][2];
#pragma unroll
    for (int mt = 0; mt < 2; ++mt)
#pragma unroll
        for (int kc = 0; kc < 2; ++kc)
            aq[mt][kc] = *(const bf16x8*)(Qh + ((size_t)bh * S_LEN + q0 + w * 32 + mt * 16 + l16) * DEPTH
                                          + kc * 32 + quad * 8);

    float lrow[2][4];
    f32x4 Oacc[2][4];
    const f32x4 z4 = {0.f, 0.f, 0.f, 0.f};
#pragma unroll
    for (int mt = 0; mt < 2; ++mt)
#pragma unroll
        for (int r = 0; r < 4; ++r) lrow[mt][r] = 0.f;
#pragma unroll
    for (int mt = 0; mt < 2; ++mt)
#pragma unroll
        for (int nt = 0; nt < 4; ++nt) Oacc[mt][nt] = z4;

    const float C2 = 0.18033688f;
    const float M2 = 17.312340f;
    const int swzk = l16 & 7;

    async16(pKn, dK0); async16(pKn + 8 * DEPTH, dK0 + 8 * 64);
    async16(pVn, dV0); async16(pVn + 8 * S_LEN, dV0 + 8 * 64);
    pKn += 64 * DEPTH; pVn += 64;
    __syncthreads();

    for (int kt = 0; kt < ntiles; ++kt) {
        const int cur = kt & 1;
        if (kt + 1 < ntiles) {
            uint16_t* dK = cur ? dK0 : dK1;
            uint16_t* dV = cur ? dV0 : dV1;
            async16(pKn, dK); async16(pKn + 8 * DEPTH, dK + 8 * 64);
            async16(pVn, dV); async16(pVn + 8 * S_LEN, dV + 8 * 64);
            pKn += 64 * DEPTH; pVn += 64;
        }
        const uint16_t* ksrc = cur ? &Ks[1][0] : &Ks[0][0];
        const uint16_t* vsrc = cur ? &Vs[1][0] : &Vs[0][0];
        const int k0 = kt * 64;

        float pen[4];
#pragma unroll
        for (int nt = 0; nt < 4; ++nt)
            pen[nt] = (k0 + nt * 16 + l16 < nbv) ? -M2 : -2e9f;

        f32x4 sacc[2][4];
#pragma unroll
        for (int mt = 0; mt < 2; ++mt)
#pragma unroll
            for (int nt = 0; nt < 4; ++nt) sacc[mt][nt] = z4;
        __builtin_amdgcn_s_setprio(1);
#pragma unroll
        for (int kc = 0; kc < 2; ++kc) {
#pragma unroll
            for (int nt = 0; nt < 4; ++nt) {
                bf16x8 bk = *(const bf16x8*)&ksrc[(nt * 16 + l16) * 64 + (((kc * 4 + quad) ^ swzk) << 3)];
#pragma unroll
                for (int mt = 0; mt < 2; ++mt)
                    sacc[mt][nt] = __builtin_amdgcn_mfma_f32_16x16x32_bf16(aq[mt][kc], bk,
                                                                           sacc[mt][nt], 0, 0, 0);
            }
        }
        __builtin_amdgcn_s_setprio(0);

        bf16x8 bvr[2][4];
#pragma unroll
        for (int kc = 0; kc < 2; ++kc)
#pragma unroll
            for (int nt = 0; nt < 4; ++nt)
                bvr[kc][nt] = *(const bf16x8*)&vsrc[(nt * 16 + l16) * 64 + (((kc * 4 + quad) ^ swzk) << 3)];

#pragma unroll
        for (int mt = 0; mt < 2; ++mt) {
#pragma unroll
            for (int r = 0; r < 4; ++r) {
                float p0 = EXP2F(fmaf(sacc[mt][0][r], C2, pen[0]));
                float p1 = EXP2F(fmaf(sacc[mt][1][r], C2, pen[1]));
                float p2 = EXP2F(fmaf(sacc[mt][2][r], C2, pen[2]));
                float p3 = EXP2F(fmaf(sacc[mt][3][r], C2, pen[3]));
                lrow[mt][r] += (p0 + p1) + (p2 + p3);
                u16x4 pk;
                pk[0] = f2bf(p0); pk[1] = f2bf(p1); pk[2] = f2bf(p2); pk[3] = f2bf(p3);
                *(u16x4*)&Ps[w][(quad * 4 + r) * 72 + l16 * 4] = pk;
            }
            __builtin_amdgcn_s_setprio(1);
#pragma unroll
            for (int kc = 0; kc < 2; ++kc) {
                bf16x8 ap = *(const bf16x8*)&Ps[w][l16 * 72 + kc * 32 + quad * 8];
#pragma unroll
                for (int nt = 0; nt < 4; ++nt)
                    Oacc[mt][nt] = __builtin_amdgcn_mfma_f32_16x16x32_bf16(ap, bvr[kc][nt],
                                                                           Oacc[mt][nt], 0, 0, 0);
            }
            __builtin_amdgcn_s_setprio(0);
        }
        __syncthreads();
    }

#pragma unroll
    for (int mt = 0; mt < 2; ++mt) {
#pragma unroll
        for (int r = 0; r < 4; ++r) {
            float rs = lrow[mt][r];
            rs += __shfl_xor(rs, 1);
            rs += __shfl_xor(rs, 2);
            rs += __shfl_xor(rs, 4);
            rs += __shfl_xor(rs, 8);
            float inv = 1.0f / rs;
            int srow = q0 + w * 32 + mt * 16 + quad * 4 + r;
            size_t base = ((size_t)bh * S_LEN + srow) * DEPTH;
#pragma unroll
            for (int nt = 0; nt < 4; ++nt)
                ctx[base + nt * 16 + l16] = f2bf(Oacc[mt][nt][r] * inv);
        }
    }
}

// ---------------------------------------------------------------------------
extern "C" void kernel_launch(void* const* d_in, const int* in_sizes, int n_in,
                              void* d_out, int out_size, void* d_ws, size_t ws_size,
                              hipStream_t stream) {
    const float* v    = (const float*)d_in[0];
    const float* k    = (const float*)d_in[1];
    const float* q    = (const float*)d_in[2];
    const float* mask = (const float*)d_in[3];
    const float* Wq   = (const float*)d_in[4];
    const float* bq   = (const float*)d_in[5];
    const float* Wk   = (const float*)d_in[6];
    const float* bk   = (const float*)d_in[7];
    const float* Wv   = (const float*)d_in[8];
    const float* bv   = (const float*)d_in[9];
    const float* Wo   = (const float*)d_in[10];
    const float* bo   = (const float*)d_in[11];

    // ws: WT4(8MB) + Qh(16MB) + gidx(32KB) + nb(16B) [+ qb,kb(32MB) if big ws]
    char* p = (char*)d_ws;
    uint16_t* WT4 = (uint16_t*)p; p += (size_t)4 * DMODEL * DMODEL * 2;
    uint16_t* Qh  = (uint16_t*)p; p += (size_t)64 * S_LEN * DEPTH * 2;
    int* gidx     = (int*)p;      p += (size_t)4 * S_LEN * 4;
    int* nb       = (int*)p;      p += 16;
    size_t used = (size_t)(p - (char*)d_ws);
    const size_t half16 = (size_t)8192 * DMODEL * 2;  // 16MB (bf16 8192x1024)

    const bool bigws = (ws_size >= used + 2 * half16);
    uint16_t *qb, *kb, *Kc, *Vc;
    if (bigws) {
        qb = (uint16_t*)((char*)d_ws + used);
        kb = qb + (size_t)8192 * DMODEL;
        Kc = (uint16_t*)d_out;                       // d_out: [Kc 16MB][Vc 16MB]
        Vc = Kc + (size_t)64 * S_LEN * DEPTH;
    } else {
        qb = (uint16_t*)d_out;                       // d_out: [qb->Kc][kb->Vc]
        kb = qb + (size_t)8192 * DMODEL;
        Kc = qb;                                     // overwrites qb after z=0
        Vc = kb;                                     // overwrites kb after z=1
    }

    mask_scan<<<4, 256, 0, stream>>>(mask, gidx, nb);
    transpose4<<<dim3(32, 32, 4), dim3(32, 8), 0, stream>>>(Wq, Wk, Wv, Wo, WT4);
    cast2<<<dim3(4096, 2), 256, 0, stream>>>(q, k, qb, kb);

    if (bigws) {
        qkv_gemm<<<dim3(8, 64, 3), 256, 0, stream>>>(qb, kb, v, WT4, bq, bk, bv,
                                                     Qh, Kc, Vc, gidx, nb, 0);
    } else {
        // sequential: z0 reads qb -> Qh; z1 reads kb -> Kc(=qb region, dead);
        // z2 reads v f32 -> Vc(=kb region, dead after z1).
        qkv_gemm<<<dim3(8, 64, 1), 256, 0, stream>>>(qb, kb, v, WT4, bq, bk, bv,
                                                     Qh, Kc, Vc, gidx, nb, 0);
        qkv_gemm<<<dim3(8, 64, 1), 256, 0, stream>>>(qb, kb, v, WT4, bq, bk, bv,
                                                     Qh, Kc, Vc, gidx, nb, 1);
        qkv_gemm<<<dim3(8, 64, 1), 256, 0, stream>>>(qb, kb, v, WT4, bq, bk, bv,
                                                     Qh, Kc, Vc, gidx, nb, 2);
    }
    zero_tails<<<64, 256, 0, stream>>>(nb, Kc, Vc);

    flash_attn<<<dim3(16, 64), 256, 0, stream>>>(Qh, Kc, Vc, nb, Qh /*ctx*/);

    out_gemm<<<dim3(8, 64), 256, 0, stream>>>(Qh, WT4 + (size_t)3 * DMODEL * DMODEL,
                                              bo, (float*)d_out);
}